// Round 2
// baseline (1965.745 us; speedup 1.0000x reference)
//
#include <hip/hip_runtime.h>
#include <hip/hip_bf16.h>

typedef __hip_bfloat16 bf16;

__device__ __forceinline__ float b2f(bf16 v) { return __bfloat162float(v); }
__device__ __forceinline__ bf16 f2b(float v) { return __float2bfloat16(v); }

// Problem constants: B=4, C=512, Ck=Cv=256, N=H*W=4096
// Inputs/outputs are FP32 (per reference dtypes). Internals: z fp32, q/k/v/ctx/P bf16.

// ---------------------------------------------------------------------------
// Kernel 1: fused QKV GEMM.  Z[o,n] = sum_c W[o,c] * x[b,c,n]
// M=768 (wq rows 0-255, wk 256-511, wv 512-767), K=512, N=4096 per batch.
// zq,zk written fp32 (no bias: BN cancels it exactly); v written bf16 with +bv.
// ---------------------------------------------------------------------------
__global__ __launch_bounds__(256) void k_gemm_qkv(
    const float* __restrict__ x, const float* __restrict__ wq,
    const float* __restrict__ wk, const float* __restrict__ wv,
    const float* __restrict__ bv,
    float* __restrict__ zq, float* __restrict__ zk, bf16* __restrict__ v)
{
  const int b  = blockIdx.z;
  const int n0 = blockIdx.x * 64;
  const int m0 = blockIdx.y * 64;            // 0..767, tile fully inside one W
  const int tid = threadIdx.x;
  const int tx = tid & 15, ty = tid >> 4;

  const float* W; int mo;
  if (m0 < 256)      { W = wq; mo = m0; }
  else if (m0 < 512) { W = wk; mo = m0 - 256; }
  else               { W = wv; mo = m0 - 512; }

  __shared__ float As[16][65];   // [k][m]  (+1 pad: stores are [cc][r] strided)
  __shared__ float Bs[16][64];   // [k][n]  (stores stride-1, no pad needed)

  float acc[4][4] = {};
  const float* xb = x + ((size_t)b << 21);   // b*512*4096

  for (int c0 = 0; c0 < 512; c0 += 16) {
#pragma unroll
    for (int t = 0; t < 4; ++t) {
      int idx = tid + t * 256;
      int r = idx >> 4, cc = idx & 15;
      As[cc][r] = W[(mo + r) * 512 + c0 + cc];
    }
#pragma unroll
    for (int t = 0; t < 4; ++t) {
      int idx = tid + t * 256;
      int r = idx >> 6, nn = idx & 63;
      Bs[r][nn] = xb[((c0 + r) << 12) + n0 + nn];
    }
    __syncthreads();
#pragma unroll
    for (int kk = 0; kk < 16; ++kk) {
      float a_[4], b_[4];
#pragma unroll
      for (int i = 0; i < 4; ++i) a_[i] = As[kk][ty + 16 * i];
#pragma unroll
      for (int j = 0; j < 4; ++j) b_[j] = Bs[kk][tx + 16 * j];
#pragma unroll
      for (int i = 0; i < 4; ++i)
#pragma unroll
        for (int j = 0; j < 4; ++j) acc[i][j] += a_[i] * b_[j];
    }
    __syncthreads();
  }

  const size_t base = ((size_t)b << 20);     // b*256*4096
  if (m0 < 512) {
    float* Z = (m0 < 256) ? zq : zk;
#pragma unroll
    for (int i = 0; i < 4; ++i) {
      int m = mo + ty + 16 * i;
#pragma unroll
      for (int j = 0; j < 4; ++j)
        Z[base + ((size_t)m << 12) + n0 + tx + 16 * j] = acc[i][j];
    }
  } else {
#pragma unroll
    for (int i = 0; i < 4; ++i) {
      int m = mo + ty + 16 * i;
      float bias = bv[m];
#pragma unroll
      for (int j = 0; j < 4; ++j)
        v[base + ((size_t)m << 12) + n0 + tx + 16 * j] = f2b(acc[i][j] + bias);
    }
  }
}

// ---------------------------------------------------------------------------
// Kernel 2: BN stats per channel over (B, N) = 16384 elements.
// stats[(t*256+c)*2] = mean, [+1] = rsqrt(var+eps). t: 0=q, 1=k.
// ---------------------------------------------------------------------------
__global__ __launch_bounds__(256) void k_bn_stats(
    const float* __restrict__ zq, const float* __restrict__ zk,
    float* __restrict__ stats)
{
  const int c = blockIdx.x;
  const int t = blockIdx.y;
  const float* z = t ? zk : zq;
  const int tid = threadIdx.x;
  float s = 0.f, ss = 0.f;
  for (int b = 0; b < 4; ++b) {
    const float* row = z + ((size_t)b << 20) + ((size_t)c << 12);
    for (int n = tid; n < 4096; n += 256) {
      float val = row[n];
      s += val; ss += val * val;
    }
  }
  for (int off = 32; off; off >>= 1) {
    s  += __shfl_down(s, off, 64);
    ss += __shfl_down(ss, off, 64);
  }
  __shared__ float sm1[4], sm2[4];
  int lane = tid & 63, wid = tid >> 6;
  if (lane == 0) { sm1[wid] = s; sm2[wid] = ss; }
  __syncthreads();
  if (tid == 0) {
    s  = sm1[0] + sm1[1] + sm1[2] + sm1[3];
    ss = sm2[0] + sm2[1] + sm2[2] + sm2[3];
    float mean = s * (1.f / 16384.f);
    float var  = ss * (1.f / 16384.f) - mean * mean;
    stats[(t * 256 + c) * 2 + 0] = mean;
    stats[(t * 256 + c) * 2 + 1] = rsqrtf(var + 1e-5f);
  }
}

// ---------------------------------------------------------------------------
// Kernel 3: q = relu((z-mean)*istd*gamma + beta) -> bf16 (same for k)
// ---------------------------------------------------------------------------
__global__ __launch_bounds__(256) void k_bn_relu(
    const float* __restrict__ zq, const float* __restrict__ zk,
    const float* __restrict__ stats,
    const float* __restrict__ gq, const float* __restrict__ betaq,
    const float* __restrict__ gk, const float* __restrict__ betak,
    bf16* __restrict__ q, bf16* __restrict__ k)
{
  const int c = blockIdx.x;
  const int b = blockIdx.y;
  const int t = blockIdx.z;
  const float* z = t ? zk : zq;
  bf16* o = t ? k : q;
  const float mean = stats[(t * 256 + c) * 2 + 0];
  const float istd = stats[(t * 256 + c) * 2 + 1];
  const float g  = t ? gk[c] : gq[c];
  const float be = t ? betak[c] : betaq[c];
  const float sc = istd * g;
  const size_t base = ((size_t)b << 20) + ((size_t)c << 12);
  for (int n = threadIdx.x; n < 4096; n += 256) {
    float val = (z[base + n] - mean) * sc + be;
    o[base + n] = f2b(fmaxf(val, 0.f));
  }
}

// ---------------------------------------------------------------------------
// Kernel 4 (per batch): S[n,m] = (1/16) * sum_c k[c,n]*q[c,m] -> P bf16
// GEMM "TN": both operands are K-major [C,N]. M-dim=n (k), N-dim=m (q), K=256.
// ---------------------------------------------------------------------------
__global__ __launch_bounds__(256) void k_scores(
    const bf16* __restrict__ q, const bf16* __restrict__ kbuf,
    bf16* __restrict__ P, int b)
{
  const int m0 = blockIdx.x * 64;   // q position (softmax axis)
  const int n0 = blockIdx.y * 64;   // k position (row of P)
  const int tid = threadIdx.x;
  const int tx = tid & 15, ty = tid >> 4;
  __shared__ float As[16][64];      // k tile [c][n] (stride-1 stores)
  __shared__ float Bs[16][64];      // q tile [c][m]
  float acc[4][4] = {};
  const bf16* kb = kbuf + ((size_t)b << 20);
  const bf16* qb = q    + ((size_t)b << 20);

  for (int c0 = 0; c0 < 256; c0 += 16) {
#pragma unroll
    for (int t = 0; t < 4; ++t) {
      int idx = tid + t * 256;
      int r = idx >> 6, nn = idx & 63;
      As[r][nn] = b2f(kb[((c0 + r) << 12) + n0 + nn]);
      Bs[r][nn] = b2f(qb[((c0 + r) << 12) + m0 + nn]);
    }
    __syncthreads();
#pragma unroll
    for (int kk = 0; kk < 16; ++kk) {
      float a_[4], b_[4];
#pragma unroll
      for (int i = 0; i < 4; ++i) a_[i] = As[kk][ty + 16 * i];
#pragma unroll
      for (int j = 0; j < 4; ++j) b_[j] = Bs[kk][tx + 16 * j];
#pragma unroll
      for (int i = 0; i < 4; ++i)
#pragma unroll
        for (int j = 0; j < 4; ++j) acc[i][j] += a_[i] * b_[j];
    }
    __syncthreads();
  }
#pragma unroll
  for (int i = 0; i < 4; ++i) {
    size_t row = (size_t)(n0 + ty + 16 * i) << 12;
#pragma unroll
    for (int j = 0; j < 4; ++j)
      P[row + m0 + tx + 16 * j] = f2b(acc[i][j] * 0.0625f);
  }
}

// ---------------------------------------------------------------------------
// Kernel 5 (per batch): softmax over m (row of P), in place.
// ---------------------------------------------------------------------------
__global__ __launch_bounds__(256) void k_softmax(bf16* __restrict__ P)
{
  const int row = blockIdx.x;
  bf16* prow = P + ((size_t)row << 12);
  const int tid = threadIdx.x;
  float v[16];
  float lmax = -1e30f;
#pragma unroll
  for (int t = 0; t < 16; ++t) {
    v[t] = b2f(prow[tid + t * 256]);
    lmax = fmaxf(lmax, v[t]);
  }
  for (int off = 32; off; off >>= 1) lmax = fmaxf(lmax, __shfl_down(lmax, off, 64));
  __shared__ float sm[4];
  int lane = tid & 63, wid = tid >> 6;
  if (lane == 0) sm[wid] = lmax;
  __syncthreads();
  const float M = fmaxf(fmaxf(sm[0], sm[1]), fmaxf(sm[2], sm[3]));
  __syncthreads();
  float s = 0.f;
#pragma unroll
  for (int t = 0; t < 16; ++t) { v[t] = __expf(v[t] - M); s += v[t]; }
  for (int off = 32; off; off >>= 1) s += __shfl_down(s, off, 64);
  if (lane == 0) sm[wid] = s;
  __syncthreads();
  const float inv = 1.f / (sm[0] + sm[1] + sm[2] + sm[3]);
#pragma unroll
  for (int t = 0; t < 16; ++t) prow[tid + t * 256] = f2b(v[t] * inv);
}

// ---------------------------------------------------------------------------
// Kernel 6 (per batch): ctx[c,n] = sum_m v[c,m] * P[n,m].
// GEMM M=c(256), N=n(4096), K=m(4096). Both operands read contiguous-in-m,
// staged transposed into LDS (padded: [mm][r] stores are stride-65).
// ---------------------------------------------------------------------------
__global__ __launch_bounds__(256) void k_ctx(
    const bf16* __restrict__ v, const bf16* __restrict__ P,
    bf16* __restrict__ ctx, int b)
{
  const int n0 = blockIdx.x * 64;
  const int c0 = blockIdx.y * 64;
  const int tid = threadIdx.x;
  const int tx = tid & 15, ty = tid >> 4;
  __shared__ float As[32][65];   // v^T tile: [m][c]
  __shared__ float Bs[32][65];   // P^T tile: [m][n]
  float acc[4][4] = {};
  const bf16* vb = v + ((size_t)b << 20);

  for (int m0 = 0; m0 < 4096; m0 += 32) {
#pragma unroll
    for (int t = 0; t < 8; ++t) {
      int idx = tid + t * 256;
      int r = idx >> 5, mm = idx & 31;     // r: 0..63
      As[mm][r] = b2f(vb[((size_t)(c0 + r) << 12) + m0 + mm]);
      Bs[mm][r] = b2f(P [((size_t)(n0 + r) << 12) + m0 + mm]);
    }
    __syncthreads();
#pragma unroll
    for (int kk = 0; kk < 32; ++kk) {
      float a_[4], b_[4];
#pragma unroll
      for (int i = 0; i < 4; ++i) a_[i] = As[kk][ty + 16 * i];
#pragma unroll
      for (int j = 0; j < 4; ++j) b_[j] = Bs[kk][tx + 16 * j];
#pragma unroll
      for (int i = 0; i < 4; ++i)
#pragma unroll
        for (int j = 0; j < 4; ++j) acc[i][j] += a_[i] * b_[j];
    }
    __syncthreads();
  }
  const size_t base = ((size_t)b << 20);
#pragma unroll
  for (int i = 0; i < 4; ++i) {
    int c = c0 + ty + 16 * i;
#pragma unroll
    for (int j = 0; j < 4; ++j)
      ctx[base + ((size_t)c << 12) + n0 + tx + 16 * j] = f2b(acc[i][j]);
  }
}

// ---------------------------------------------------------------------------
// Kernel 7: out[b,o,n] = sum_cv wW[o,cv]*ctx[b,cv,n] + bW[o] + x[b,o,n]
// M=512, K=256, N=4096 per batch. fp32 output.
// ---------------------------------------------------------------------------
__global__ __launch_bounds__(256) void k_out(
    const float* __restrict__ wW, const float* __restrict__ bW,
    const bf16* __restrict__ ctx, const float* __restrict__ x,
    float* __restrict__ out)
{
  const int b  = blockIdx.z;
  const int n0 = blockIdx.x * 64;
  const int m0 = blockIdx.y * 64;
  const int tid = threadIdx.x;
  const int tx = tid & 15, ty = tid >> 4;
  __shared__ float As[16][65];   // wW tile [cv][o] (strided stores, padded)
  __shared__ float Bs[16][64];   // ctx tile [cv][n]
  float acc[4][4] = {};
  const bf16* cb = ctx + ((size_t)b << 20);

  for (int c0 = 0; c0 < 256; c0 += 16) {
#pragma unroll
    for (int t = 0; t < 4; ++t) {
      int idx = tid + t * 256;
      { int r = idx >> 4, cc = idx & 15;
        As[cc][r] = wW[(m0 + r) * 256 + c0 + cc]; }
      { int r = idx >> 6, nn = idx & 63;
        Bs[r][nn] = b2f(cb[((size_t)(c0 + r) << 12) + n0 + nn]); }
    }
    __syncthreads();
#pragma unroll
    for (int kk = 0; kk < 16; ++kk) {
      float a_[4], b_[4];
#pragma unroll
      for (int i = 0; i < 4; ++i) a_[i] = As[kk][ty + 16 * i];
#pragma unroll
      for (int j = 0; j < 4; ++j) b_[j] = Bs[kk][tx + 16 * j];
#pragma unroll
      for (int i = 0; i < 4; ++i)
#pragma unroll
        for (int j = 0; j < 4; ++j) acc[i][j] += a_[i] * b_[j];
    }
    __syncthreads();
  }
#pragma unroll
  for (int i = 0; i < 4; ++i) {
    int m = m0 + ty + 16 * i;
    float bias = bW[m];
#pragma unroll
    for (int j = 0; j < 4; ++j) {
      size_t idx = ((size_t)b << 21) + ((size_t)m << 12) + n0 + tx + 16 * j;
      out[idx] = acc[i][j] + bias + x[idx];
    }
  }
}

// ---------------------------------------------------------------------------
extern "C" void kernel_launch(void* const* d_in, const int* in_sizes, int n_in,
                              void* d_out, int out_size, void* d_ws, size_t ws_size,
                              hipStream_t stream)
{
  const float* x     = (const float*)d_in[0];
  const float* wq    = (const float*)d_in[1];
  // d_in[2] = bq: cancelled exactly by BN mean-subtraction
  const float* gq    = (const float*)d_in[3];
  const float* betaq = (const float*)d_in[4];
  const float* wk    = (const float*)d_in[5];
  // d_in[6] = bk: cancelled
  const float* gk    = (const float*)d_in[7];
  const float* betak = (const float*)d_in[8];
  const float* wv    = (const float*)d_in[9];
  const float* bv    = (const float*)d_in[10];
  const float* wW    = (const float*)d_in[11];
  const float* bW    = (const float*)d_in[12];
  float* out = (float*)d_out;

  // workspace layout (total ~96 MiB)
  char* ws = (char*)d_ws;
  float* zq   = (float*)(ws);                    // 16 MiB  fp32 [4,256,4096]
  float* zk   = (float*)(ws + 16777216);         // 16 MiB
  bf16*  q    = (bf16*) (ws + 33554432);         //  8 MiB  bf16 [4,256,4096]
  bf16*  kbuf = (bf16*) (ws + 41943040);         //  8 MiB
  bf16*  v    = (bf16*) (ws + 50331648);         //  8 MiB
  bf16*  ctx  = (bf16*) (ws + 58720256);         //  8 MiB
  float* stats= (float*)(ws + 67108864);         //  4 KiB  (mean,istd)x512
  bf16*  P    = (bf16*) (ws + 67112960);         // 32 MiB  bf16 [4096,4096] (1 batch)

  k_gemm_qkv<<<dim3(64, 12, 4), 256, 0, stream>>>(x, wq, wk, wv, bv, zq, zk, v);
  k_bn_stats<<<dim3(256, 2), 256, 0, stream>>>(zq, zk, stats);
  k_bn_relu<<<dim3(256, 4, 2), 256, 0, stream>>>(zq, zk, stats, gq, betaq, gk, betak, q, kbuf);
  for (int b = 0; b < 4; ++b) {
    k_scores <<<dim3(64, 64), 256, 0, stream>>>(q, kbuf, P, b);
    k_softmax<<<4096, 256, 0, stream>>>(P);
    k_ctx    <<<dim3(64, 4), 256, 0, stream>>>(v, P, ctx, b);
  }
  k_out<<<dim3(64, 8, 4), 256, 0, stream>>>(wW, bW, ctx, x, out);
}

// Round 3
// 684.193 us; speedup vs baseline: 2.8731x; 2.8731x over previous
//
#include <hip/hip_runtime.h>

typedef __attribute__((ext_vector_type(8))) __bf16 bfx8;
typedef __attribute__((ext_vector_type(4))) float f32x4;

__device__ __forceinline__ float s2f(unsigned short s) {
  return __uint_as_float((unsigned int)s << 16);
}
__device__ __forceinline__ unsigned short f2s(float f) {
  unsigned int u = __float_as_uint(f);
  u += 0x7FFFu + ((u >> 16) & 1u);     // round-to-nearest-even
  return (unsigned short)(u >> 16);
}

// ---------------------------------------------------------------------------
// Generic MFMA GEMM core. Both operands stored [row][k], k-contiguous.
// Computes D[m][n] = sum_k Ag[m][k] * Bg[n][k]  (i.e. A · B_stored^T).
// 256 threads = 4 waves arranged 2x2; wave tile = (BM/2)x(BN/2).
// Fragment layouts (m89/m91/m120-verified):
//   A/B: lane holds row/col = lane&15, k = (lane>>4)*8 + j  (8 contig bf16)
//   C/D: col = lane&15, row = (lane>>4)*4 + reg
// LDS rows padded +8 halves: stride 144B -> 4-bank step -> <=2-way (free).
// ---------------------------------------------------------------------------
template<int BM, int BN, int BK>
__device__ __forceinline__ void gemm_core(
    const unsigned short* __restrict__ Ag, int lda,
    const unsigned short* __restrict__ Bg, int ldb, int K,
    unsigned short* As, unsigned short* Bs, f32x4* acc)
{
  constexpr int WM = BM / 2, WN = BN / 2;
  constexpr int MT = WM / 16, NT = WN / 16;
  constexpr int LD = BK + 8;
  constexpr int VPR = BK / 8;                 // 16B vectors per row
  constexpr int PA = (BM * BK) / (256 * 8);
  constexpr int PB = (BN * BK) / (256 * 8);
  const int tid  = threadIdx.x;
  const int lane = tid & 63, wave = tid >> 6;
  const int lr = lane & 15, quad = lane >> 4;
  const int wm = (wave >> 1) * WM, wn = (wave & 1) * WN;

  for (int k0 = 0; k0 < K; k0 += BK) {
#pragma unroll
    for (int p = 0; p < PA; ++p) {
      int vv = tid + p * 256;
      int r = vv / VPR, kc = (vv % VPR) * 8;
      *(uint4*)(As + r * LD + kc) = *(const uint4*)(Ag + (size_t)r * lda + k0 + kc);
    }
#pragma unroll
    for (int p = 0; p < PB; ++p) {
      int vv = tid + p * 256;
      int r = vv / VPR, kc = (vv % VPR) * 8;
      *(uint4*)(Bs + r * LD + kc) = *(const uint4*)(Bg + (size_t)r * ldb + k0 + kc);
    }
    __syncthreads();
#pragma unroll
    for (int kk = 0; kk < BK; kk += 32) {
      bfx8 af[MT], bfr[NT];
#pragma unroll
      for (int i = 0; i < MT; ++i)
        af[i] = *(const bfx8*)(As + (wm + i * 16 + lr) * LD + kk + quad * 8);
#pragma unroll
      for (int j = 0; j < NT; ++j)
        bfr[j] = *(const bfx8*)(Bs + (wn + j * 16 + lr) * LD + kk + quad * 8);
#pragma unroll
      for (int i = 0; i < MT; ++i)
#pragma unroll
        for (int j = 0; j < NT; ++j)
          acc[i * NT + j] = __builtin_amdgcn_mfma_f32_16x16x32_bf16(
              af[i], bfr[j], acc[i * NT + j], 0, 0, 0);
    }
    __syncthreads();
  }
}

// ---------------------------------------------------------------------------
// x [4][512][4096] fp32 -> x_t [4][4096][512] bf16 (LDS-tiled transpose)
// ---------------------------------------------------------------------------
__global__ __launch_bounds__(256) void k_xt(const float* __restrict__ x,
                                            unsigned short* __restrict__ xt)
{
  __shared__ float t[64][65];
  const int b = blockIdx.z, c0 = blockIdx.y * 64, n0 = blockIdx.x * 64;
  const float* xb = x + ((size_t)b << 21);
  const int tid = threadIdx.x;
  const int hi = tid >> 6, lo = tid & 63;
#pragma unroll
  for (int p = 0; p < 16; ++p)
    t[hi + p * 4][lo] = xb[(size_t)(c0 + hi + p * 4) * 4096 + n0 + lo];
  __syncthreads();
  unsigned short* xtb = xt + ((size_t)b << 21);
#pragma unroll
  for (int p = 0; p < 16; ++p)
    xtb[(size_t)(n0 + hi + p * 4) * 512 + c0 + lo] = f2s(t[lo][hi + p * 4]);
}

// ---------------------------------------------------------------------------
// Weight convert: wqk[512][512] (q rows 0-255, k rows 256-511), wv[256][512],
// wW[512][256], all bf16.
// ---------------------------------------------------------------------------
__global__ __launch_bounds__(256) void k_wcvt(
    const float* __restrict__ wq, const float* __restrict__ wk,
    const float* __restrict__ wv, const float* __restrict__ wW,
    unsigned short* __restrict__ wqk, unsigned short* __restrict__ wvb,
    unsigned short* __restrict__ wWb)
{
  int i = blockIdx.x * 256 + threadIdx.x;         // grid 1024 -> i < 262144
  wqk[i] = f2s(i < 131072 ? wq[i] : wk[i - 131072]);
  if (i < 131072) { wvb[i] = f2s(wv[i]); wWb[i] = f2s(wW[i]); }
}

// ---------------------------------------------------------------------------
// z_t[b][n][o] = sum_c x_t[b][n][c] * wqk[o][c]   (M=n 4096, N=o 512, K=512)
// ---------------------------------------------------------------------------
__global__ __launch_bounds__(256) void k_qk(
    const unsigned short* __restrict__ xt, const unsigned short* __restrict__ wqk,
    unsigned short* __restrict__ zt)
{
  __shared__ unsigned short As[128 * 72], Bs[128 * 72];
  f32x4 acc[16] = {};
  const int b = blockIdx.z, n0 = blockIdx.x * 128, o0 = blockIdx.y * 128;
  gemm_core<128, 128, 64>(xt + ((size_t)b * 4096 + n0) * 512, 512,
                          wqk + (size_t)o0 * 512, 512, 512, As, Bs, acc);
  const int lane = threadIdx.x & 63, wave = threadIdx.x >> 6;
  const int lr = lane & 15, quad = lane >> 4;
  const int wm = (wave >> 1) * 64, wn = (wave & 1) * 64;
#pragma unroll
  for (int i = 0; i < 4; ++i)
#pragma unroll
    for (int j = 0; j < 4; ++j)
#pragma unroll
      for (int r = 0; r < 4; ++r) {
        int row = wm + i * 16 + quad * 4 + r, col = wn + j * 16 + lr;
        zt[((size_t)b * 4096 + n0 + row) * 512 + o0 + col] = f2s(acc[i * 4 + j][r]);
      }
}

// ---------------------------------------------------------------------------
// v[b][cv][n] = sum_c wv[cv][c] * x_t[b][n][c] + bv[cv]  (M=cv 256, N=n 4096)
// ---------------------------------------------------------------------------
__global__ __launch_bounds__(256) void k_vg(
    const unsigned short* __restrict__ xt, const unsigned short* __restrict__ wvb,
    const float* __restrict__ bv, unsigned short* __restrict__ v)
{
  __shared__ unsigned short As[64 * 72], Bs[128 * 72];
  f32x4 acc[8] = {};
  const int b = blockIdx.z, cv0 = blockIdx.y * 64, n0 = blockIdx.x * 128;
  gemm_core<64, 128, 64>(wvb + (size_t)cv0 * 512, 512,
                         xt + ((size_t)b * 4096 + n0) * 512, 512, 512, As, Bs, acc);
  const int lane = threadIdx.x & 63, wave = threadIdx.x >> 6;
  const int lr = lane & 15, quad = lane >> 4;
  const int wm = (wave >> 1) * 32, wn = (wave & 1) * 64;
#pragma unroll
  for (int i = 0; i < 2; ++i)
#pragma unroll
    for (int j = 0; j < 4; ++j)
#pragma unroll
      for (int r = 0; r < 4; ++r) {
        int row = wm + i * 16 + quad * 4 + r, col = wn + j * 16 + lr;
        v[((size_t)b * 256 + cv0 + row) * 4096 + n0 + col] =
            f2s(acc[i * 4 + j][r] + bv[cv0 + row]);
      }
}

// ---------------------------------------------------------------------------
// BN stats: per channel o (0..511) accumulate sum/sumsq over 16384 rows of z_t.
// 128 blocks x 128 rows; thread t handles channels t and t+256; atomicAdd.
// ---------------------------------------------------------------------------
__global__ __launch_bounds__(256) void k_stats(
    const unsigned short* __restrict__ zt, float* __restrict__ stats_raw)
{
  const int t = threadIdx.x;
  const unsigned short* base = zt + (size_t)blockIdx.x * 128 * 512;
  float s0 = 0.f, ss0 = 0.f, s1 = 0.f, ss1 = 0.f;
  for (int r = 0; r < 128; ++r) {
    float a = s2f(base[r * 512 + t]);
    float c = s2f(base[r * 512 + t + 256]);
    s0 += a; ss0 += a * a; s1 += c; ss1 += c * c;
  }
  atomicAdd(&stats_raw[t * 2], s0);
  atomicAdd(&stats_raw[t * 2 + 1], ss0);
  atomicAdd(&stats_raw[(t + 256) * 2], s1);
  atomicAdd(&stats_raw[(t + 256) * 2 + 1], ss1);
}

// ---------------------------------------------------------------------------
// BN+ReLU: q_t[n][c] / k_t[n][c] bf16 from z_t columns. 256 blocks x 64 rows.
// ---------------------------------------------------------------------------
__global__ __launch_bounds__(256) void k_bnrelu(
    const unsigned short* __restrict__ zt, const float* __restrict__ stats_raw,
    const float* __restrict__ gq, const float* __restrict__ betaq,
    const float* __restrict__ gk, const float* __restrict__ betak,
    unsigned short* __restrict__ qt, unsigned short* __restrict__ kt)
{
  const int t = threadIdx.x;
  const float mA = stats_raw[t * 2] * (1.f / 16384.f);
  const float vA = stats_raw[t * 2 + 1] * (1.f / 16384.f) - mA * mA;
  const float scA = rsqrtf(vA + 1e-5f) * gq[t], beA = betaq[t];
  const float mB = stats_raw[(t + 256) * 2] * (1.f / 16384.f);
  const float vB = stats_raw[(t + 256) * 2 + 1] * (1.f / 16384.f) - mB * mB;
  const float scB = rsqrtf(vB + 1e-5f) * gk[t], beB = betak[t];
  const int r0 = blockIdx.x * 64;
  for (int r = r0; r < r0 + 64; ++r) {
    float a = s2f(zt[(size_t)r * 512 + t]);
    qt[(size_t)r * 256 + t] = f2s(fmaxf((a - mA) * scA + beA, 0.f));
    float c = s2f(zt[(size_t)r * 512 + t + 256]);
    kt[(size_t)r * 256 + t] = f2s(fmaxf((c - mB) * scB + beB, 0.f));
  }
}

// ---------------------------------------------------------------------------
// Scores (per batch): P[n][m] = (1/16) sum_c k_t[n][c] q_t[m][c]
// ---------------------------------------------------------------------------
__global__ __launch_bounds__(256) void k_sc(
    const unsigned short* __restrict__ qt, const unsigned short* __restrict__ kt,
    unsigned short* __restrict__ P, int b)
{
  __shared__ unsigned short As[128 * 72], Bs[128 * 72];
  f32x4 acc[16] = {};
  const int m0 = blockIdx.x * 128, n0 = blockIdx.y * 128;
  gemm_core<128, 128, 64>(kt + ((size_t)b * 4096 + n0) * 256, 256,
                          qt + ((size_t)b * 4096 + m0) * 256, 256, 256, As, Bs, acc);
  const int lane = threadIdx.x & 63, wave = threadIdx.x >> 6;
  const int lr = lane & 15, quad = lane >> 4;
  const int wm = (wave >> 1) * 64, wn = (wave & 1) * 64;
#pragma unroll
  for (int i = 0; i < 4; ++i)
#pragma unroll
    for (int j = 0; j < 4; ++j)
#pragma unroll
      for (int r = 0; r < 4; ++r) {
        int row = wm + i * 16 + quad * 4 + r, col = wn + j * 16 + lr;
        P[(size_t)(n0 + row) * 4096 + m0 + col] = f2s(acc[i * 4 + j][r] * 0.0625f);
      }
}

// ---------------------------------------------------------------------------
// Softmax over m (row of P), in place.
// ---------------------------------------------------------------------------
__global__ __launch_bounds__(256) void k_softmax(unsigned short* __restrict__ P)
{
  unsigned short* prow = P + ((size_t)blockIdx.x << 12);
  const int tid = threadIdx.x;
  float v[16];
  float lmax = -1e30f;
#pragma unroll
  for (int t = 0; t < 16; ++t) {
    v[t] = s2f(prow[tid + t * 256]);
    lmax = fmaxf(lmax, v[t]);
  }
  for (int off = 32; off; off >>= 1) lmax = fmaxf(lmax, __shfl_down(lmax, off, 64));
  __shared__ float sm[4];
  int lane = tid & 63, wid = tid >> 6;
  if (lane == 0) sm[wid] = lmax;
  __syncthreads();
  const float M = fmaxf(fmaxf(sm[0], sm[1]), fmaxf(sm[2], sm[3]));
  __syncthreads();
  float s = 0.f;
#pragma unroll
  for (int t = 0; t < 16; ++t) { v[t] = __expf(v[t] - M); s += v[t]; }
  for (int off = 32; off; off >>= 1) s += __shfl_down(s, off, 64);
  if (lane == 0) sm[wid] = s;
  __syncthreads();
  const float inv = 1.f / (sm[0] + sm[1] + sm[2] + sm[3]);
#pragma unroll
  for (int t = 0; t < 16; ++t) prow[tid + t * 256] = f2s(v[t] * inv);
}

// ---------------------------------------------------------------------------
// Context (per batch): ctx_t[n][c] = sum_m P[n][m] v[c][m]  (M=n, N=c, K=4096)
// ---------------------------------------------------------------------------
__global__ __launch_bounds__(256) void k_cx(
    const unsigned short* __restrict__ P, const unsigned short* __restrict__ v,
    unsigned short* __restrict__ ctx, int b)
{
  __shared__ unsigned short As[64 * 72], Bs[64 * 72];
  f32x4 acc[4] = {};
  const int c0 = blockIdx.x * 64, n0 = blockIdx.y * 64;
  gemm_core<64, 64, 64>(P + (size_t)n0 * 4096, 4096,
                        v + ((size_t)b * 256 + c0) * 4096, 4096, 4096, As, Bs, acc);
  const int lane = threadIdx.x & 63, wave = threadIdx.x >> 6;
  const int lr = lane & 15, quad = lane >> 4;
  const int wm = (wave >> 1) * 32, wn = (wave & 1) * 32;
#pragma unroll
  for (int i = 0; i < 2; ++i)
#pragma unroll
    for (int j = 0; j < 2; ++j)
#pragma unroll
      for (int r = 0; r < 4; ++r) {
        int row = wm + i * 16 + quad * 4 + r, col = wn + j * 16 + lr;
        ctx[((size_t)b * 4096 + n0 + row) * 256 + c0 + col] = f2s(acc[i * 2 + j][r]);
      }
}

// ---------------------------------------------------------------------------
// Out: out[b][o][n] = sum_cv wW[o][cv] ctx_t[b][n][cv] + bW[o] + x[b][o][n]
// ---------------------------------------------------------------------------
__global__ __launch_bounds__(256) void k_out(
    const unsigned short* __restrict__ wWb, const float* __restrict__ bW,
    const unsigned short* __restrict__ ctx, const float* __restrict__ x,
    float* __restrict__ out)
{
  __shared__ unsigned short As[128 * 72], Bs[128 * 72];
  f32x4 acc[16] = {};
  const int b = blockIdx.z, n0 = blockIdx.x * 128, o0 = blockIdx.y * 128;
  gemm_core<128, 128, 64>(wWb + (size_t)o0 * 256, 256,
                          ctx + ((size_t)b * 4096 + n0) * 256, 256, 256, As, Bs, acc);
  const int lane = threadIdx.x & 63, wave = threadIdx.x >> 6;
  const int lr = lane & 15, quad = lane >> 4;
  const int wm = (wave >> 1) * 64, wn = (wave & 1) * 64;
#pragma unroll
  for (int i = 0; i < 4; ++i)
#pragma unroll
    for (int j = 0; j < 4; ++j)
#pragma unroll
      for (int r = 0; r < 4; ++r) {
        int row = wm + i * 16 + quad * 4 + r, col = wn + j * 16 + lr;
        size_t idx = ((size_t)b * 512 + o0 + row) * 4096 + n0 + col;
        out[idx] = acc[i * 4 + j][r] + bW[o0 + row] + x[idx];
      }
}

// ---------------------------------------------------------------------------
extern "C" void kernel_launch(void* const* d_in, const int* in_sizes, int n_in,
                              void* d_out, int out_size, void* d_ws, size_t ws_size,
                              hipStream_t stream)
{
  const float* x     = (const float*)d_in[0];
  const float* wq    = (const float*)d_in[1];
  // d_in[2] = bq: cancelled exactly by BN mean-subtraction
  const float* gq    = (const float*)d_in[3];
  const float* betaq = (const float*)d_in[4];
  const float* wk    = (const float*)d_in[5];
  // d_in[6] = bk: cancelled
  const float* gk    = (const float*)d_in[7];
  const float* betak = (const float*)d_in[8];
  const float* wv    = (const float*)d_in[9];
  const float* bv    = (const float*)d_in[10];
  const float* wW    = (const float*)d_in[11];
  const float* bW    = (const float*)d_in[12];
  float* out = (float*)d_out;

  // workspace layout (total 68,161,536 B ~ 65 MiB; P aliases dead x_t/z_t)
  char* ws = (char*)d_ws;
  unsigned short* xt   = (unsigned short*)(ws);              // 16 MiB [4,4096,512]
  unsigned short* zt   = (unsigned short*)(ws + 16777216);   // 16 MiB [4,4096,512]
  unsigned short* qt   = (unsigned short*)(ws + 33554432);   //  8 MiB [16384,256]
  unsigned short* kt   = (unsigned short*)(ws + 41943040);   //  8 MiB
  unsigned short* v    = (unsigned short*)(ws + 50331648);   //  8 MiB [4,256,4096]
  unsigned short* ctx  = (unsigned short*)(ws + 58720256);   //  8 MiB [16384,256]
  unsigned short* wqk  = (unsigned short*)(ws + 67108864);   // 512 KiB [512,512]
  unsigned short* wvb  = (unsigned short*)(ws + 67633152);   // 256 KiB [256,512]
  unsigned short* wWb  = (unsigned short*)(ws + 67895296);   // 256 KiB [512,256]
  float*          stat = (float*)         (ws + 68157440);   //   4 KiB
  unsigned short* P    = (unsigned short*)(ws);              // 32 MiB, aliases xt+zt
                                                             // (both dead before k_sc)

  hipMemsetAsync(stat, 0, 4096, stream);
  k_xt  <<<dim3(64, 8, 4), 256, 0, stream>>>(x, xt);
  k_wcvt<<<1024, 256, 0, stream>>>(wq, wk, wv, wW, wqk, wvb, wWb);
  k_qk  <<<dim3(32, 4, 4), 256, 0, stream>>>(xt, wqk, zt);
  k_vg  <<<dim3(32, 4, 4), 256, 0, stream>>>(xt, wvb, bv, v);
  k_stats<<<128, 256, 0, stream>>>(zt, stat);
  k_bnrelu<<<256, 256, 0, stream>>>(zt, stat, gq, betaq, gk, betak, qt, kt);
  for (int b = 0; b < 4; ++b) {
    k_sc     <<<dim3(32, 32), 256, 0, stream>>>(qt, kt, P, b);
    k_softmax<<<4096, 256, 0, stream>>>(P);
    k_cx     <<<dim3(4, 64), 256, 0, stream>>>(P, v, ctx, b);
  }
  k_out <<<dim3(32, 4, 4), 256, 0, stream>>>(wWb, bW, ctx, x, out);
}

// Round 4
// 484.391 us; speedup vs baseline: 4.0582x; 1.4125x over previous
//
#include <hip/hip_runtime.h>

typedef __attribute__((ext_vector_type(8))) __bf16 bfx8;
typedef __attribute__((ext_vector_type(4))) float f32x4;

__device__ __forceinline__ float s2f(unsigned short s) {
  return __uint_as_float((unsigned int)s << 16);
}
__device__ __forceinline__ unsigned short f2s(float f) {
  unsigned int u = __float_as_uint(f);
  u += 0x7FFFu + ((u >> 16) & 1u);     // round-to-nearest-even
  return (unsigned short)(u >> 16);
}

// ---------------------------------------------------------------------------
// Generic MFMA GEMM core. Both operands stored [row][k], k-contiguous.
// Computes D[m][n] = sum_k Ag[m][k] * Bg[n][k]  (i.e. A · B_stored^T).
// 256 threads = 4 waves arranged 2x2; wave tile = (BM/2)x(BN/2).
// Fragment layouts (m89/m91/m120-verified):
//   A/B: lane holds row/col = lane&15, k = (lane>>4)*8 + j  (8 contig bf16)
//   C/D: col = lane&15, row = (lane>>4)*4 + reg
// LDS rows padded +8 halves: stride 144B -> 4-bank step -> mostly-free.
// ---------------------------------------------------------------------------
template<int BM, int BN, int BK>
__device__ __forceinline__ void gemm_core(
    const unsigned short* __restrict__ Ag, int lda,
    const unsigned short* __restrict__ Bg, int ldb, int K,
    unsigned short* As, unsigned short* Bs, f32x4* acc)
{
  constexpr int WM = BM / 2, WN = BN / 2;
  constexpr int MT = WM / 16, NT = WN / 16;
  constexpr int LD = BK + 8;
  constexpr int VPR = BK / 8;                 // 16B vectors per row
  constexpr int PA = (BM * BK) / (256 * 8);
  constexpr int PB = (BN * BK) / (256 * 8);
  const int tid  = threadIdx.x;
  const int lane = tid & 63, wave = tid >> 6;
  const int lr = lane & 15, quad = lane >> 4;
  const int wm = (wave >> 1) * WM, wn = (wave & 1) * WN;

  for (int k0 = 0; k0 < K; k0 += BK) {
#pragma unroll
    for (int p = 0; p < PA; ++p) {
      int vv = tid + p * 256;
      int r = vv / VPR, kc = (vv % VPR) * 8;
      *(uint4*)(As + r * LD + kc) = *(const uint4*)(Ag + (size_t)r * lda + k0 + kc);
    }
#pragma unroll
    for (int p = 0; p < PB; ++p) {
      int vv = tid + p * 256;
      int r = vv / VPR, kc = (vv % VPR) * 8;
      *(uint4*)(Bs + r * LD + kc) = *(const uint4*)(Bg + (size_t)r * ldb + k0 + kc);
    }
    __syncthreads();
#pragma unroll
    for (int kk = 0; kk < BK; kk += 32) {
      bfx8 af[MT], bfr[NT];
#pragma unroll
      for (int i = 0; i < MT; ++i)
        af[i] = *(const bfx8*)(As + (wm + i * 16 + lr) * LD + kk + quad * 8);
#pragma unroll
      for (int j = 0; j < NT; ++j)
        bfr[j] = *(const bfx8*)(Bs + (wn + j * 16 + lr) * LD + kk + quad * 8);
#pragma unroll
      for (int i = 0; i < MT; ++i)
#pragma unroll
        for (int j = 0; j < NT; ++j)
          acc[i * NT + j] = __builtin_amdgcn_mfma_f32_16x16x32_bf16(
              af[i], bfr[j], acc[i * NT + j], 0, 0, 0);
    }
    __syncthreads();
  }
}

// ---------------------------------------------------------------------------
// x [4][512][4096] fp32 -> x_t [4][4096][512] bf16 (LDS-tiled transpose)
// ---------------------------------------------------------------------------
__global__ __launch_bounds__(256) void k_xt(const float* __restrict__ x,
                                            unsigned short* __restrict__ xt)
{
  __shared__ float t[64][65];
  const int b = blockIdx.z, c0 = blockIdx.y * 64, n0 = blockIdx.x * 64;
  const float* xb = x + ((size_t)b << 21);
  const int tid = threadIdx.x;
  const int hi = tid >> 6, lo = tid & 63;
#pragma unroll
  for (int p = 0; p < 16; ++p)
    t[hi + p * 4][lo] = xb[(size_t)(c0 + hi + p * 4) * 4096 + n0 + lo];
  __syncthreads();
  unsigned short* xtb = xt + ((size_t)b << 21);
#pragma unroll
  for (int p = 0; p < 16; ++p)
    xtb[(size_t)(n0 + hi + p * 4) * 512 + c0 + lo] = f2s(t[lo][hi + p * 4]);
}

// ---------------------------------------------------------------------------
// Weight convert: wqk[512][512] (q rows 0-255, k rows 256-511), wv[256][512],
// wW[512][256], all bf16.
// ---------------------------------------------------------------------------
__global__ __launch_bounds__(256) void k_wcvt(
    const float* __restrict__ wq, const float* __restrict__ wk,
    const float* __restrict__ wv, const float* __restrict__ wW,
    unsigned short* __restrict__ wqk, unsigned short* __restrict__ wvb,
    unsigned short* __restrict__ wWb)
{
  int i = blockIdx.x * 256 + threadIdx.x;         // grid 1024 -> i < 262144
  wqk[i] = f2s(i < 131072 ? wq[i] : wk[i - 131072]);
  if (i < 131072) { wvb[i] = f2s(wv[i]); wWb[i] = f2s(wW[i]); }
}

// ---------------------------------------------------------------------------
// z_t[b][n][o] = sum_c x_t[b][n][c] * wqk[o][c]   (M=n 4096, N=o 512, K=512)
// ---------------------------------------------------------------------------
__global__ __launch_bounds__(256) void k_qk(
    const unsigned short* __restrict__ xt, const unsigned short* __restrict__ wqk,
    unsigned short* __restrict__ zt)
{
  __shared__ unsigned short As[128 * 72], Bs[128 * 72];
  f32x4 acc[16] = {};
  const int b = blockIdx.z, n0 = blockIdx.x * 128, o0 = blockIdx.y * 128;
  gemm_core<128, 128, 64>(xt + ((size_t)b * 4096 + n0) * 512, 512,
                          wqk + (size_t)o0 * 512, 512, 512, As, Bs, acc);
  const int lane = threadIdx.x & 63, wave = threadIdx.x >> 6;
  const int lr = lane & 15, quad = lane >> 4;
  const int wm = (wave >> 1) * 64, wn = (wave & 1) * 64;
#pragma unroll
  for (int i = 0; i < 4; ++i)
#pragma unroll
    for (int j = 0; j < 4; ++j)
#pragma unroll
      for (int r = 0; r < 4; ++r) {
        int row = wm + i * 16 + quad * 4 + r, col = wn + j * 16 + lr;
        zt[((size_t)b * 4096 + n0 + row) * 512 + o0 + col] = f2s(acc[i * 4 + j][r]);
      }
}

// ---------------------------------------------------------------------------
// v[b][cv][n] = sum_c wv[cv][c] * x_t[b][n][c] + bv[cv]  (M=cv 256, N=n 4096)
// ---------------------------------------------------------------------------
__global__ __launch_bounds__(256) void k_vg(
    const unsigned short* __restrict__ xt, const unsigned short* __restrict__ wvb,
    const float* __restrict__ bv, unsigned short* __restrict__ v)
{
  __shared__ unsigned short As[64 * 72], Bs[128 * 72];
  f32x4 acc[8] = {};
  const int b = blockIdx.z, cv0 = blockIdx.y * 64, n0 = blockIdx.x * 128;
  gemm_core<64, 128, 64>(wvb + (size_t)cv0 * 512, 512,
                         xt + ((size_t)b * 4096 + n0) * 512, 512, 512, As, Bs, acc);
  const int lane = threadIdx.x & 63, wave = threadIdx.x >> 6;
  const int lr = lane & 15, quad = lane >> 4;
  const int wm = (wave >> 1) * 32, wn = (wave & 1) * 64;
#pragma unroll
  for (int i = 0; i < 2; ++i)
#pragma unroll
    for (int j = 0; j < 4; ++j)
#pragma unroll
      for (int r = 0; r < 4; ++r) {
        int row = wm + i * 16 + quad * 4 + r, col = wn + j * 16 + lr;
        v[((size_t)b * 256 + cv0 + row) * 4096 + n0 + col] =
            f2s(acc[i * 4 + j][r] + bv[cv0 + row]);
      }
}

// ---------------------------------------------------------------------------
// BN stats: per channel o (0..511) accumulate sum/sumsq over 16384 rows of z_t.
// ---------------------------------------------------------------------------
__global__ __launch_bounds__(256) void k_stats(
    const unsigned short* __restrict__ zt, float* __restrict__ stats_raw)
{
  const int t = threadIdx.x;
  const unsigned short* base = zt + (size_t)blockIdx.x * 128 * 512;
  float s0 = 0.f, ss0 = 0.f, s1 = 0.f, ss1 = 0.f;
  for (int r = 0; r < 128; ++r) {
    float a = s2f(base[r * 512 + t]);
    float c = s2f(base[r * 512 + t + 256]);
    s0 += a; ss0 += a * a; s1 += c; ss1 += c * c;
  }
  atomicAdd(&stats_raw[t * 2], s0);
  atomicAdd(&stats_raw[t * 2 + 1], ss0);
  atomicAdd(&stats_raw[(t + 256) * 2], s1);
  atomicAdd(&stats_raw[(t + 256) * 2 + 1], ss1);
}

// ---------------------------------------------------------------------------
// BN+ReLU: q_t[n][c] / k_t[n][c] bf16 from z_t columns.
// ---------------------------------------------------------------------------
__global__ __launch_bounds__(256) void k_bnrelu(
    const unsigned short* __restrict__ zt, const float* __restrict__ stats_raw,
    const float* __restrict__ gq, const float* __restrict__ betaq,
    const float* __restrict__ gk, const float* __restrict__ betak,
    unsigned short* __restrict__ qt, unsigned short* __restrict__ kt)
{
  const int t = threadIdx.x;
  const float mA = stats_raw[t * 2] * (1.f / 16384.f);
  const float vA = stats_raw[t * 2 + 1] * (1.f / 16384.f) - mA * mA;
  const float scA = rsqrtf(vA + 1e-5f) * gq[t], beA = betaq[t];
  const float mB = stats_raw[(t + 256) * 2] * (1.f / 16384.f);
  const float vB = stats_raw[(t + 256) * 2 + 1] * (1.f / 16384.f) - mB * mB;
  const float scB = rsqrtf(vB + 1e-5f) * gk[t], beB = betak[t];
  const int r0 = blockIdx.x * 64;
  for (int r = r0; r < r0 + 64; ++r) {
    float a = s2f(zt[(size_t)r * 512 + t]);
    qt[(size_t)r * 256 + t] = f2s(fmaxf((a - mA) * scA + beA, 0.f));
    float c = s2f(zt[(size_t)r * 512 + t + 256]);
    kt[(size_t)r * 256 + t] = f2s(fmaxf((c - mB) * scB + beB, 0.f));
  }
}

// ---------------------------------------------------------------------------
// Scores+exp (per batch): P[n][m] = exp(s/16 - 20), s = sum_c kt[n][c] qt[m][c]
// Fixed-shift softmax: q,k >= 0 so s in [0, ~30]; exp(s/16-20) never
// over/underflows and softmax is shift-invariant -> exact. Row sums l[n]
// accumulated over the bf16-ROUNDED p (consistency with k_cx's P reads).
// ---------------------------------------------------------------------------
__global__ __launch_bounds__(256) void k_sc(
    const unsigned short* __restrict__ qt, const unsigned short* __restrict__ kt,
    unsigned short* __restrict__ P, float* __restrict__ l, int b)
{
  __shared__ unsigned short As[128 * 72], Bs[128 * 72];
  f32x4 acc[16] = {};
  const int m0 = blockIdx.x * 128, n0 = blockIdx.y * 128;
  gemm_core<128, 128, 64>(kt + ((size_t)b * 4096 + n0) * 256, 256,
                          qt + ((size_t)b * 4096 + m0) * 256, 256, 256, As, Bs, acc);
  const int lane = threadIdx.x & 63, wave = threadIdx.x >> 6;
  const int lr = lane & 15, quad = lane >> 4;
  const int wm = (wave >> 1) * 64, wn = (wave & 1) * 64;
#pragma unroll
  for (int i = 0; i < 4; ++i)
#pragma unroll
    for (int r = 0; r < 4; ++r) {
      int row = wm + i * 16 + quad * 4 + r;
      float rs = 0.f;
#pragma unroll
      for (int j = 0; j < 4; ++j) {
        float p = __expf(acc[i * 4 + j][r] * 0.0625f - 20.f);
        unsigned short ps = f2s(p);
        P[(size_t)(n0 + row) * 4096 + m0 + wn + j * 16 + lr] = ps;
        rs += s2f(ps);
      }
      rs += __shfl_down(rs, 8, 16);
      rs += __shfl_down(rs, 4, 16);
      rs += __shfl_down(rs, 2, 16);
      rs += __shfl_down(rs, 1, 16);
      if (lr == 0) atomicAdd(&l[n0 + row], rs);
    }
}

// ---------------------------------------------------------------------------
// Context partials (per batch, K-split 4): for m-range [split*1024, +1024):
//   opart[split][n][c] = sum_m P[n][m] v[c][m]   (fp32, plain stores)
// grid (4 splits, 32 n-tiles, 4 c-tiles), tile 128n x 64c -> 512 blocks.
// ---------------------------------------------------------------------------
__global__ __launch_bounds__(256) void k_cx(
    const unsigned short* __restrict__ P, const unsigned short* __restrict__ v,
    float* __restrict__ opart, int b)
{
  __shared__ unsigned short As[128 * 72], Bs[64 * 72];
  f32x4 acc[8] = {};
  const int split = blockIdx.x, n0 = blockIdx.y * 128, c0 = blockIdx.z * 64;
  const int m0 = split * 1024;
  gemm_core<128, 64, 64>(P + (size_t)n0 * 4096 + m0, 4096,
                         v + ((size_t)b * 256 + c0) * 4096 + m0, 4096, 1024,
                         As, Bs, acc);
  const int lane = threadIdx.x & 63, wave = threadIdx.x >> 6;
  const int lr = lane & 15, quad = lane >> 4;
  const int wm = (wave >> 1) * 64, wn = (wave & 1) * 32;
  float* op = opart + (size_t)split * 1048576;
#pragma unroll
  for (int i = 0; i < 4; ++i)
#pragma unroll
    for (int j = 0; j < 2; ++j)
#pragma unroll
      for (int r = 0; r < 4; ++r) {
        int row = wm + i * 16 + quad * 4 + r, col = wn + j * 16 + lr;
        op[(size_t)(n0 + row) * 256 + c0 + col] = acc[i * 2 + j][r];
      }
}

// ---------------------------------------------------------------------------
// Reduce splits + softmax-normalize: ctx_t[n][c] = (sum_s opart[s][n][c])/l[n]
// One block per n (256 threads = 256 c). Coalesced.
// ---------------------------------------------------------------------------
__global__ __launch_bounds__(256) void k_red(
    const float* __restrict__ opart, const float* __restrict__ l,
    unsigned short* __restrict__ ctx)
{
  const int n = blockIdx.x, c = threadIdx.x;
  const size_t idx = (size_t)n * 256 + c;
  float s = opart[idx] + opart[idx + 1048576] + opart[idx + 2097152]
          + opart[idx + 3145728];
  ctx[idx] = f2s(s / l[n]);
}

// ---------------------------------------------------------------------------
// Out: out[b][o][n] = sum_cv wW[o][cv] ctx_t[b][n][cv] + bW[o] + x[b][o][n]
// ---------------------------------------------------------------------------
__global__ __launch_bounds__(256) void k_out(
    const unsigned short* __restrict__ wWb, const float* __restrict__ bW,
    const unsigned short* __restrict__ ctx, const float* __restrict__ x,
    float* __restrict__ out)
{
  __shared__ unsigned short As[128 * 72], Bs[128 * 72];
  f32x4 acc[16] = {};
  const int b = blockIdx.z, n0 = blockIdx.x * 128, o0 = blockIdx.y * 128;
  gemm_core<128, 128, 64>(wWb + (size_t)o0 * 256, 256,
                          ctx + ((size_t)b * 4096 + n0) * 256, 256, 256, As, Bs, acc);
  const int lane = threadIdx.x & 63, wave = threadIdx.x >> 6;
  const int lr = lane & 15, quad = lane >> 4;
  const int wm = (wave >> 1) * 64, wn = (wave & 1) * 64;
#pragma unroll
  for (int i = 0; i < 4; ++i)
#pragma unroll
    for (int j = 0; j < 4; ++j)
#pragma unroll
      for (int r = 0; r < 4; ++r) {
        int row = wm + i * 16 + quad * 4 + r, col = wn + j * 16 + lr;
        size_t idx = ((size_t)b * 512 + o0 + row) * 4096 + n0 + col;
        out[idx] = acc[i * 4 + j][r] + bW[o0 + row] + x[idx];
      }
}

// ---------------------------------------------------------------------------
extern "C" void kernel_launch(void* const* d_in, const int* in_sizes, int n_in,
                              void* d_out, int out_size, void* d_ws, size_t ws_size,
                              hipStream_t stream)
{
  const float* x     = (const float*)d_in[0];
  const float* wq    = (const float*)d_in[1];
  // d_in[2] = bq: cancelled exactly by BN mean-subtraction
  const float* gq    = (const float*)d_in[3];
  const float* betaq = (const float*)d_in[4];
  const float* wk    = (const float*)d_in[5];
  // d_in[6] = bk: cancelled
  const float* gk    = (const float*)d_in[7];
  const float* betak = (const float*)d_in[8];
  const float* wv    = (const float*)d_in[9];
  const float* bv    = (const float*)d_in[10];
  const float* wW    = (const float*)d_in[11];
  const float* bW    = (const float*)d_in[12];
  float* out = (float*)d_out;

  // workspace layout (~81 MiB total; P aliases dead x_t/z_t)
  char* ws = (char*)d_ws;
  unsigned short* xt   = (unsigned short*)(ws);              // 16 MiB [4,4096,512]
  unsigned short* zt   = (unsigned short*)(ws + 16777216);   // 16 MiB [4,4096,512]
  unsigned short* qt   = (unsigned short*)(ws + 33554432);   //  8 MiB [16384,256]
  unsigned short* kt   = (unsigned short*)(ws + 41943040);   //  8 MiB
  unsigned short* v    = (unsigned short*)(ws + 50331648);   //  8 MiB [4,256,4096]
  unsigned short* ctx  = (unsigned short*)(ws + 58720256);   //  8 MiB [16384,256]
  unsigned short* wqk  = (unsigned short*)(ws + 67108864);   // 512 KiB [512,512]
  unsigned short* wvb  = (unsigned short*)(ws + 67633152);   // 256 KiB [256,512]
  unsigned short* wWb  = (unsigned short*)(ws + 67895296);   // 256 KiB [512,256]
  float*          stat = (float*)         (ws + 68157440);   //   4 KiB
  float*          lsum = (float*)         (ws + 68161536);   //  64 KiB [4][4096]
  float*          opart= (float*)         (ws + 68227072);   //  16 MiB [4][4096][256]
  unsigned short* P    = (unsigned short*)(ws);              // 32 MiB, aliases xt+zt
                                                             // (both dead before k_sc)

  hipMemsetAsync(stat, 0, 4096, stream);
  hipMemsetAsync(lsum, 0, 65536, stream);
  k_xt  <<<dim3(64, 8, 4), 256, 0, stream>>>(x, xt);
  k_wcvt<<<1024, 256, 0, stream>>>(wq, wk, wv, wW, wqk, wvb, wWb);
  k_qk  <<<dim3(32, 4, 4), 256, 0, stream>>>(xt, wqk, zt);
  k_vg  <<<dim3(32, 4, 4), 256, 0, stream>>>(xt, wvb, bv, v);
  k_stats<<<128, 256, 0, stream>>>(zt, stat);
  k_bnrelu<<<256, 256, 0, stream>>>(zt, stat, gq, betaq, gk, betak, qt, kt);
  for (int b = 0; b < 4; ++b) {
    k_sc <<<dim3(32, 32), 256, 0, stream>>>(qt, kt, P, lsum + b * 4096, b);
    k_cx <<<dim3(4, 32, 4), 256, 0, stream>>>(P, v, opart, b);
    k_red<<<4096, 256, 0, stream>>>(opart, lsum + b * 4096,
                                    ctx + (size_t)b * 1048576);
  }
  k_out <<<dim3(32, 4, 4), 256, 0, stream>>>(wWb, bW, ctx, x, out);
}

// Round 5
// 319.048 us; speedup vs baseline: 6.1613x; 1.5182x over previous
//
#include <hip/hip_runtime.h>

typedef __attribute__((ext_vector_type(8))) __bf16 bfx8;
typedef __attribute__((ext_vector_type(4))) float f32x4;

__device__ __forceinline__ float s2f(unsigned short s) {
  return __uint_as_float((unsigned int)s << 16);
}
__device__ __forceinline__ unsigned short f2s(float f) {
  unsigned int u = __float_as_uint(f);
  u += 0x7FFFu + ((u >> 16) & 1u);     // round-to-nearest-even
  return (unsigned short)(u >> 16);
}

// ---------------------------------------------------------------------------
// Async MFMA GEMM core (m97-style global_load_lds staging, XOR-swizzled).
// Both operands stored [row][k] k-contiguous in global. Computes
// D[m][n] = sum_k Ag[m][k]*Bg[n][k]. 256 thr = 4 waves 2x2, tile 128x128.
//
// Staging: global_load_lds width=16; DMA writes lane i -> ldsbase + 16*i
// (wave-uniform base, no scatter). Each 1024B segment = 8 rows x 128B.
// Lane fetches global vec (lane&7)^(lane>>3), so LDS slot (row,s) holds
// global vec s^(row&7).
// Read: lane wants global (row = *+lr, vec = quad+kv) -> slot (quad+kv)^(lr&7);
// bank group = 4*slot mod 32 -> 8 groups x 2 rows = 2-way (free, m136).
// ---------------------------------------------------------------------------
template<int BM, int BN, int BK>
__device__ __forceinline__ void gemm_core_async(
    const unsigned short* __restrict__ Ag, int lda,
    const unsigned short* __restrict__ Bg, int ldb, int K,
    unsigned short* As, unsigned short* Bs, f32x4* acc)
{
  static_assert(BK == 64, "BK must be 64 (128B rows)");
  constexpr int WM = BM / 2, WN = BN / 2;
  constexpr int MT = WM / 16, NT = WN / 16;
  constexpr int SA = BM / 8, SB = BN / 8;   // 1024B segments per tile
  const int tid = threadIdx.x;
  const int lane = tid & 63, wave = tid >> 6;
  const int lr = lane & 15, quad = lane >> 4;
  const int sw = lr & 7;
  const int rl = lane >> 3;                  // row within segment (0..7)
  const int vg = (lane & 7) ^ rl;            // swizzled global vec index
  const int wm = (wave >> 1) * WM, wn = (wave & 1) * WN;

  for (int k0 = 0; k0 < K; k0 += BK) {
#pragma unroll
    for (int s = wave; s < SA; s += 4) {
      const unsigned short* g = Ag + (size_t)(s * 8 + rl) * lda + k0 + vg * 8;
      __builtin_amdgcn_global_load_lds(
          (__attribute__((address_space(1))) void*)g,
          (__attribute__((address_space(3))) void*)(As + s * 512), 16, 0, 0);
    }
#pragma unroll
    for (int s = wave; s < SB; s += 4) {
      const unsigned short* g = Bg + (size_t)(s * 8 + rl) * ldb + k0 + vg * 8;
      __builtin_amdgcn_global_load_lds(
          (__attribute__((address_space(1))) void*)g,
          (__attribute__((address_space(3))) void*)(Bs + s * 512), 16, 0, 0);
    }
    __syncthreads();
#pragma unroll
    for (int kk = 0; kk < BK; kk += 32) {
      const int kv = kk >> 3;                // 0 or 4
      bfx8 af[MT], bfr[NT];
#pragma unroll
      for (int i = 0; i < MT; ++i)
        af[i] = *(const bfx8*)(As + (wm + i * 16 + lr) * BK
                               + (((quad + kv) ^ sw) << 3));
#pragma unroll
      for (int j = 0; j < NT; ++j)
        bfr[j] = *(const bfx8*)(Bs + (wn + j * 16 + lr) * BK
                                + (((quad + kv) ^ sw) << 3));
#pragma unroll
      for (int i = 0; i < MT; ++i)
#pragma unroll
        for (int j = 0; j < NT; ++j)
          acc[i * NT + j] = __builtin_amdgcn_mfma_f32_16x16x32_bf16(
              af[i], bfr[j], acc[i * NT + j], 0, 0, 0);
    }
    __syncthreads();
  }
}

// ---------------------------------------------------------------------------
// x [4][512][4096] fp32 -> x_t [4][4096][512] bf16 (LDS-tiled transpose)
// ---------------------------------------------------------------------------
__global__ __launch_bounds__(256) void k_xt(const float* __restrict__ x,
                                            unsigned short* __restrict__ xt)
{
  __shared__ float t[64][65];
  const int b = blockIdx.z, c0 = blockIdx.y * 64, n0 = blockIdx.x * 64;
  const float* xb = x + ((size_t)b << 21);
  const int tid = threadIdx.x;
  const int hi = tid >> 6, lo = tid & 63;
#pragma unroll
  for (int p = 0; p < 16; ++p)
    t[hi + p * 4][lo] = xb[(size_t)(c0 + hi + p * 4) * 4096 + n0 + lo];
  __syncthreads();
  unsigned short* xtb = xt + ((size_t)b << 21);
#pragma unroll
  for (int p = 0; p < 16; ++p)
    xtb[(size_t)(n0 + hi + p * 4) * 512 + c0 + lo] = f2s(t[lo][hi + p * 4]);
}

// ---------------------------------------------------------------------------
// Weight convert: wqk[512][512] (q rows 0-255, k rows 256-511), wv[256][512],
// wW[512][256], all bf16.
// ---------------------------------------------------------------------------
__global__ __launch_bounds__(256) void k_wcvt(
    const float* __restrict__ wq, const float* __restrict__ wk,
    const float* __restrict__ wv, const float* __restrict__ wW,
    unsigned short* __restrict__ wqk, unsigned short* __restrict__ wvb,
    unsigned short* __restrict__ wWb)
{
  int i = blockIdx.x * 256 + threadIdx.x;         // grid 1024 -> i < 262144
  wqk[i] = f2s(i < 131072 ? wq[i] : wk[i - 131072]);
  if (i < 131072) { wvb[i] = f2s(wv[i]); wWb[i] = f2s(wW[i]); }
}

// ---------------------------------------------------------------------------
// z_t[b][n][o] = sum_c x_t[b][n][c] * wqk[o][c]   (M=n 4096, N=o 512, K=512)
// ---------------------------------------------------------------------------
__global__ __launch_bounds__(256) void k_qk(
    const unsigned short* __restrict__ xt, const unsigned short* __restrict__ wqk,
    unsigned short* __restrict__ zt)
{
  __shared__ __align__(16) unsigned short As[128 * 64], Bs[128 * 64];
  f32x4 acc[16] = {};
  const int b = blockIdx.z, n0 = blockIdx.x * 128, o0 = blockIdx.y * 128;
  gemm_core_async<128, 128, 64>(xt + ((size_t)b * 4096 + n0) * 512, 512,
                                wqk + (size_t)o0 * 512, 512, 512, As, Bs, acc);
  const int lane = threadIdx.x & 63, wave = threadIdx.x >> 6;
  const int lr = lane & 15, quad = lane >> 4;
  const int wm = (wave >> 1) * 64, wn = (wave & 1) * 64;
#pragma unroll
  for (int i = 0; i < 4; ++i)
#pragma unroll
    for (int j = 0; j < 4; ++j)
#pragma unroll
      for (int r = 0; r < 4; ++r) {
        int row = wm + i * 16 + quad * 4 + r, col = wn + j * 16 + lr;
        zt[((size_t)b * 4096 + n0 + row) * 512 + o0 + col] = f2s(acc[i * 4 + j][r]);
      }
}

// ---------------------------------------------------------------------------
// v[b][cv][n] = sum_c wv[cv][c] * x_t[b][n][c] + bv[cv]  (tile 128cv x 128n)
// ---------------------------------------------------------------------------
__global__ __launch_bounds__(256) void k_vg(
    const unsigned short* __restrict__ xt, const unsigned short* __restrict__ wvb,
    const float* __restrict__ bv, unsigned short* __restrict__ v)
{
  __shared__ __align__(16) unsigned short As[128 * 64], Bs[128 * 64];
  f32x4 acc[16] = {};
  const int b = blockIdx.z, cv0 = blockIdx.y * 128, n0 = blockIdx.x * 128;
  gemm_core_async<128, 128, 64>(wvb + (size_t)cv0 * 512, 512,
                                xt + ((size_t)b * 4096 + n0) * 512, 512, 512,
                                As, Bs, acc);
  const int lane = threadIdx.x & 63, wave = threadIdx.x >> 6;
  const int lr = lane & 15, quad = lane >> 4;
  const int wm = (wave >> 1) * 64, wn = (wave & 1) * 64;
#pragma unroll
  for (int i = 0; i < 4; ++i)
#pragma unroll
    for (int j = 0; j < 4; ++j)
#pragma unroll
      for (int r = 0; r < 4; ++r) {
        int row = wm + i * 16 + quad * 4 + r, col = wn + j * 16 + lr;
        v[((size_t)b * 256 + cv0 + row) * 4096 + n0 + col] =
            f2s(acc[i * 4 + j][r] + bv[cv0 + row]);
      }
}

// ---------------------------------------------------------------------------
// BN stats: per channel o (0..511) accumulate sum/sumsq over 16384 rows of z_t.
// ---------------------------------------------------------------------------
__global__ __launch_bounds__(256) void k_stats(
    const unsigned short* __restrict__ zt, float* __restrict__ stats_raw)
{
  const int t = threadIdx.x;
  const unsigned short* base = zt + (size_t)blockIdx.x * 128 * 512;
  float s0 = 0.f, ss0 = 0.f, s1 = 0.f, ss1 = 0.f;
  for (int r = 0; r < 128; ++r) {
    float a = s2f(base[r * 512 + t]);
    float c = s2f(base[r * 512 + t + 256]);
    s0 += a; ss0 += a * a; s1 += c; ss1 += c * c;
  }
  atomicAdd(&stats_raw[t * 2], s0);
  atomicAdd(&stats_raw[t * 2 + 1], ss0);
  atomicAdd(&stats_raw[(t + 256) * 2], s1);
  atomicAdd(&stats_raw[(t + 256) * 2 + 1], ss1);
}

// ---------------------------------------------------------------------------
// BN+ReLU: q_t[n][c] / k_t[n][c] bf16 from z_t columns.
// ---------------------------------------------------------------------------
__global__ __launch_bounds__(256) void k_bnrelu(
    const unsigned short* __restrict__ zt, const float* __restrict__ stats_raw,
    const float* __restrict__ gq, const float* __restrict__ betaq,
    const float* __restrict__ gk, const float* __restrict__ betak,
    unsigned short* __restrict__ qt, unsigned short* __restrict__ kt)
{
  const int t = threadIdx.x;
  const float mA = stats_raw[t * 2] * (1.f / 16384.f);
  const float vA = stats_raw[t * 2 + 1] * (1.f / 16384.f) - mA * mA;
  const float scA = rsqrtf(vA + 1e-5f) * gq[t], beA = betaq[t];
  const float mB = stats_raw[(t + 256) * 2] * (1.f / 16384.f);
  const float vB = stats_raw[(t + 256) * 2 + 1] * (1.f / 16384.f) - mB * mB;
  const float scB = rsqrtf(vB + 1e-5f) * gk[t], beB = betak[t];
  const int r0 = blockIdx.x * 64;
  for (int r = r0; r < r0 + 64; ++r) {
    float a = s2f(zt[(size_t)r * 512 + t]);
    qt[(size_t)r * 256 + t] = f2s(fmaxf((a - mA) * scA + beA, 0.f));
    float c = s2f(zt[(size_t)r * 512 + t + 256]);
    kt[(size_t)r * 256 + t] = f2s(fmaxf((c - mB) * scB + beB, 0.f));
  }
}

// ---------------------------------------------------------------------------
// Scores+exp (all batches): P[b][n][m] = exp(s/16 - 20),
// s = sum_c kt[b,n][c] qt[b,m][c]. Fixed-shift softmax (q,k>=0 -> s in
// [0,~30]; shift-invariant, never over/underflows). Row sums l accumulated
// over the bf16-ROUNDED p for exact consistency with k_cx's P reads.
// ---------------------------------------------------------------------------
__global__ __launch_bounds__(256) void k_sc(
    const unsigned short* __restrict__ qt, const unsigned short* __restrict__ kt,
    unsigned short* __restrict__ P, float* __restrict__ lsum)
{
  __shared__ __align__(16) unsigned short As[128 * 64], Bs[128 * 64];
  f32x4 acc[16] = {};
  const int b = blockIdx.z, m0 = blockIdx.x * 128, n0 = blockIdx.y * 128;
  gemm_core_async<128, 128, 64>(kt + ((size_t)b * 4096 + n0) * 256, 256,
                                qt + ((size_t)b * 4096 + m0) * 256, 256, 256,
                                As, Bs, acc);
  const int lane = threadIdx.x & 63, wave = threadIdx.x >> 6;
  const int lr = lane & 15, quad = lane >> 4;
  const int wm = (wave >> 1) * 64, wn = (wave & 1) * 64;
  unsigned short* Pb = P + (size_t)b * 16777216;
  float* l = lsum + b * 4096;
#pragma unroll
  for (int i = 0; i < 4; ++i)
#pragma unroll
    for (int r = 0; r < 4; ++r) {
      int row = wm + i * 16 + quad * 4 + r;
      float rs = 0.f;
#pragma unroll
      for (int j = 0; j < 4; ++j) {
        float p = __expf(acc[i * 4 + j][r] * 0.0625f - 20.f);
        unsigned short ps = f2s(p);
        Pb[(size_t)(n0 + row) * 4096 + m0 + wn + j * 16 + lr] = ps;
        rs += s2f(ps);
      }
      rs += __shfl_down(rs, 8, 16);
      rs += __shfl_down(rs, 4, 16);
      rs += __shfl_down(rs, 2, 16);
      rs += __shfl_down(rs, 1, 16);
      if (lr == 0) atomicAdd(&l[n0 + row], rs);
    }
}

// ---------------------------------------------------------------------------
// Context partials (all batches, K-split 4): m-range [split*1024, +1024):
//   opart[split][b][n][c] = sum_m P[b][n][m] v[b][c][m]  (fp32)
// grid (4 splits, 32 n-tiles, b*2+ctile), tile 128n x 128c -> 1024 blocks.
// ---------------------------------------------------------------------------
__global__ __launch_bounds__(256) void k_cx(
    const unsigned short* __restrict__ P, const unsigned short* __restrict__ v,
    float* __restrict__ opart)
{
  __shared__ __align__(16) unsigned short As[128 * 64], Bs[128 * 64];
  f32x4 acc[16] = {};
  const int split = blockIdx.x, n0 = blockIdx.y * 128;
  const int b = blockIdx.z >> 1, c0 = (blockIdx.z & 1) * 128;
  const int m0 = split * 1024;
  gemm_core_async<128, 128, 64>(
      P + ((size_t)b * 4096 + n0) * 4096 + m0, 4096,
      v + ((size_t)b * 256 + c0) * 4096 + m0, 4096, 1024, As, Bs, acc);
  const int lane = threadIdx.x & 63, wave = threadIdx.x >> 6;
  const int lr = lane & 15, quad = lane >> 4;
  const int wm = (wave >> 1) * 64, wn = (wave & 1) * 64;
  float* op = opart + (size_t)(split * 4 + b) * 1048576;
#pragma unroll
  for (int i = 0; i < 4; ++i)
#pragma unroll
    for (int j = 0; j < 4; ++j)
#pragma unroll
      for (int r = 0; r < 4; ++r) {
        int row = wm + i * 16 + quad * 4 + r, col = wn + j * 16 + lr;
        op[(size_t)(n0 + row) * 256 + c0 + col] = acc[i * 4 + j][r];
      }
}

// ---------------------------------------------------------------------------
// Reduce splits + softmax-normalize: ctx[b,n][c] = (sum_s opart[s][b][n][c])/l
// grid 16384 blocks (b*4096+n), 256 threads (c). Coalesced.
// ---------------------------------------------------------------------------
__global__ __launch_bounds__(256) void k_red(
    const float* __restrict__ opart, const float* __restrict__ lsum,
    unsigned short* __restrict__ ctx)
{
  const int g = blockIdx.x, c = threadIdx.x;     // g = b*4096 + n
  const int b = g >> 12;
  const size_t idx = (size_t)g * 256 + c;
  const size_t pidx = ((size_t)b * 1048576) + ((size_t)(g & 4095)) * 256 + c;
  float s = opart[pidx] + opart[pidx + 4194304] + opart[pidx + 8388608]
          + opart[pidx + 12582912];
  ctx[idx] = f2s(s / lsum[g]);
}

// ---------------------------------------------------------------------------
// Out: out[b][o][n] = sum_cv wW[o][cv] ctx[b,n][cv] + bW[o] + x[b][o][n]
// ---------------------------------------------------------------------------
__global__ __launch_bounds__(256) void k_out(
    const unsigned short* __restrict__ wWb, const float* __restrict__ bW,
    const unsigned short* __restrict__ ctx, const float* __restrict__ x,
    float* __restrict__ out)
{
  __shared__ __align__(16) unsigned short As[128 * 64], Bs[128 * 64];
  f32x4 acc[16] = {};
  const int b = blockIdx.z, n0 = blockIdx.x * 128, o0 = blockIdx.y * 128;
  gemm_core_async<128, 128, 64>(wWb + (size_t)o0 * 256, 256,
                                ctx + ((size_t)b * 4096 + n0) * 256, 256, 256,
                                As, Bs, acc);
  const int lane = threadIdx.x & 63, wave = threadIdx.x >> 6;
  const int lr = lane & 15, quad = lane >> 4;
  const int wm = (wave >> 1) * 64, wn = (wave & 1) * 64;
#pragma unroll
  for (int i = 0; i < 4; ++i)
#pragma unroll
    for (int j = 0; j < 4; ++j)
#pragma unroll
      for (int r = 0; r < 4; ++r) {
        int row = wm + i * 16 + quad * 4 + r, col = wn + j * 16 + lr;
        size_t idx = ((size_t)b * 512 + o0 + row) * 4096 + n0 + col;
        out[idx] = acc[i * 4 + j][r] + bW[o0 + row] + x[idx];
      }
}

// ---------------------------------------------------------------------------
extern "C" void kernel_launch(void* const* d_in, const int* in_sizes, int n_in,
                              void* d_out, int out_size, void* d_ws, size_t ws_size,
                              hipStream_t stream)
{
  const float* x     = (const float*)d_in[0];
  const float* wq    = (const float*)d_in[1];
  // d_in[2] = bq: cancelled exactly by BN mean-subtraction
  const float* gq    = (const float*)d_in[3];
  const float* betaq = (const float*)d_in[4];
  const float* wk    = (const float*)d_in[5];
  // d_in[6] = bk: cancelled
  const float* gk    = (const float*)d_in[7];
  const float* betak = (const float*)d_in[8];
  const float* wv    = (const float*)d_in[9];
  const float* bv    = (const float*)d_in[10];
  const float* wW    = (const float*)d_in[11];
  const float* bW    = (const float*)d_in[12];
  float* out = (float*)d_out;

  // workspace layout (ws_size = 256 MiB, confirmed by poison-fill WRITE_SIZE)
  char* ws = (char*)d_ws;
  unsigned short* qt   = (unsigned short*)(ws);              //  8 MiB [4*4096,256]
  unsigned short* kt   = (unsigned short*)(ws + 8388608);    //  8 MiB
  unsigned short* v    = (unsigned short*)(ws + 16777216);   //  8 MiB [4,256,4096]
  unsigned short* ctx  = (unsigned short*)(ws + 25165824);   //  8 MiB [4*4096,256]
  unsigned short* wqk  = (unsigned short*)(ws + 33554432);   // 512 KiB [512,512]
  unsigned short* wvb  = (unsigned short*)(ws + 34078720);   // 256 KiB [256,512]
  unsigned short* wWb  = (unsigned short*)(ws + 34340864);   // 256 KiB [512,256]
  float*          stat = (float*)         (ws + 34603008);   //   4 KiB
  float*          lsum = (float*)         (ws + 34607104);   //  64 KiB [4][4096]
  float*          opart= (float*)         (ws + 35651584);   //  64 MiB [4][4][4096][256]
  unsigned short* xt   = (unsigned short*)(ws + 35651584);   // 16 MiB, aliases opart
  unsigned short* zt   = (unsigned short*)(ws + 52428800);   // 16 MiB, aliases opart
                                                             // (xt dead after k_vg,
                                                             //  zt dead after k_bnrelu,
                                                             //  both before k_cx)
  unsigned short* P    = (unsigned short*)(ws + 102760448);  // 128 MiB [4,4096,4096]

  hipMemsetAsync(stat, 0, 69632, stream);   // stat (4K) + pad + lsum (64K)
  k_xt   <<<dim3(64, 8, 4), 256, 0, stream>>>(x, xt);
  k_wcvt <<<1024, 256, 0, stream>>>(wq, wk, wv, wW, wqk, wvb, wWb);
  k_qk   <<<dim3(32, 4, 4), 256, 0, stream>>>(xt, wqk, zt);
  k_vg   <<<dim3(32, 2, 4), 256, 0, stream>>>(xt, wvb, bv, v);
  k_stats<<<128, 256, 0, stream>>>(zt, stat);
  k_bnrelu<<<256, 256, 0, stream>>>(zt, stat, gq, betaq, gk, betak, qt, kt);
  k_sc   <<<dim3(32, 32, 4), 256, 0, stream>>>(qt, kt, P, lsum);
  k_cx   <<<dim3(4, 32, 8), 256, 0, stream>>>(P, v, opart);
  k_red  <<<16384, 256, 0, stream>>>(opart, lsum, ctx);
  k_out  <<<dim3(32, 4, 4), 256, 0, stream>>>(wWb, bW, ctx, x, out);
}

// Round 7
// 310.499 us; speedup vs baseline: 6.3309x; 1.0275x over previous
//
#include <hip/hip_runtime.h>

typedef __attribute__((ext_vector_type(8))) __bf16 bfx8;
typedef __attribute__((ext_vector_type(4))) float f32x4;

__device__ __forceinline__ float s2f(unsigned short s) {
  return __uint_as_float((unsigned int)s << 16);
}
// round-half-up bf16 convert: 2 VALU ops (vs 5 for RNE); differs from RNE only
// at exact ties -> accuracy-neutral here, and we have 3.5x threshold margin.
__device__ __forceinline__ unsigned short f2s(float f) {
  return (unsigned short)((__float_as_uint(f) + 0x8000u) >> 16);
}

// ---------------------------------------------------------------------------
// Async MFMA GEMM core (m97-style global_load_lds staging, XOR-swizzled).
// Both operands stored [row][k] k-contiguous in global. Computes
// D[m][n] = sum_k Ag[m][k]*Bg[n][k]. 256 thr = 4 waves 2x2.
//
// Staging: global_load_lds width=16; DMA writes lane i -> ldsbase + 16*i
// (wave-uniform base, no scatter). Each 1024B segment = 8 rows x 128B.
// Lane fetches global vec (lane&7)^(lane>>3), so LDS slot (row,s) holds
// global vec s^(row&7).
// Read: lane wants global (row = *+lr, vec = quad+kv) -> slot (quad+kv)^(lr&7);
// bank group = 4*slot mod 32 -> 8 groups x 2 rows = 2-way (free, m136).
// Verified R5: SQ_LDS_BANK_CONFLICT == 0, absmax unchanged.
// ---------------------------------------------------------------------------
template<int BM, int BN, int BK>
__device__ __forceinline__ void gemm_core_async(
    const unsigned short* __restrict__ Ag, int lda,
    const unsigned short* __restrict__ Bg, int ldb, int K,
    unsigned short* As, unsigned short* Bs, f32x4* acc)
{
  static_assert(BK == 64, "BK must be 64 (128B rows)");
  constexpr int WM = BM / 2, WN = BN / 2;
  constexpr int MT = WM / 16, NT = WN / 16;
  constexpr int SA = BM / 8, SB = BN / 8;   // 1024B segments per tile
  const int tid = threadIdx.x;
  const int lane = tid & 63, wave = tid >> 6;
  const int lr = lane & 15, quad = lane >> 4;
  const int sw = lr & 7;
  const int rl = lane >> 3;                  // row within segment (0..7)
  const int vg = (lane & 7) ^ rl;            // swizzled global vec index
  const int wm = (wave >> 1) * WM, wn = (wave & 1) * WN;

  for (int k0 = 0; k0 < K; k0 += BK) {
#pragma unroll
    for (int s = wave; s < SA; s += 4) {
      const unsigned short* g = Ag + (size_t)(s * 8 + rl) * lda + k0 + vg * 8;
      __builtin_amdgcn_global_load_lds(
          (__attribute__((address_space(1))) void*)g,
          (__attribute__((address_space(3))) void*)(As + s * 512), 16, 0, 0);
    }
#pragma unroll
    for (int s = wave; s < SB; s += 4) {
      const unsigned short* g = Bg + (size_t)(s * 8 + rl) * ldb + k0 + vg * 8;
      __builtin_amdgcn_global_load_lds(
          (__attribute__((address_space(1))) void*)g,
          (__attribute__((address_space(3))) void*)(Bs + s * 512), 16, 0, 0);
    }
    __syncthreads();
#pragma unroll
    for (int kk = 0; kk < BK; kk += 32) {
      const int kv = kk >> 3;                // 0 or 4
      bfx8 af[MT], bfr[NT];
#pragma unroll
      for (int i = 0; i < MT; ++i)
        af[i] = *(const bfx8*)(As + (wm + i * 16 + lr) * BK
                               + (((quad + kv) ^ sw) << 3));
#pragma unroll
      for (int j = 0; j < NT; ++j)
        bfr[j] = *(const bfx8*)(Bs + (wn + j * 16 + lr) * BK
                                + (((quad + kv) ^ sw) << 3));
#pragma unroll
      for (int i = 0; i < MT; ++i)
#pragma unroll
        for (int j = 0; j < NT; ++j)
          acc[i * NT + j] = __builtin_amdgcn_mfma_f32_16x16x32_bf16(
              af[i], bfr[j], acc[i * NT + j], 0, 0, 0);
    }
    __syncthreads();
  }
}

// ---------------------------------------------------------------------------
// k_pre: fused (a) x [4][512][4096] fp32 -> x_t [4][4096][512] bf16 transpose
// (blocks 0..2047) and (b) weight converts (blocks 2048..3071).
// ---------------------------------------------------------------------------
__global__ __launch_bounds__(256) void k_pre(
    const float* __restrict__ x, unsigned short* __restrict__ xt,
    const float* __restrict__ wq, const float* __restrict__ wk,
    const float* __restrict__ wv, const float* __restrict__ wW,
    unsigned short* __restrict__ wqk, unsigned short* __restrict__ wvb,
    unsigned short* __restrict__ wWb)
{
  const int bid = blockIdx.x, tid = threadIdx.x;
  if (bid < 2048) {
    __shared__ float t[64][65];
    const int b = bid >> 9, c0 = ((bid >> 6) & 7) * 64, n0 = (bid & 63) * 64;
    const float* xb = x + ((size_t)b << 21);
    const int hi = tid >> 6, lo = tid & 63;
#pragma unroll
    for (int p = 0; p < 16; ++p)
      t[hi + p * 4][lo] = xb[(size_t)(c0 + hi + p * 4) * 4096 + n0 + lo];
    __syncthreads();
    unsigned short* xtb = xt + ((size_t)b << 21);
#pragma unroll
    for (int p = 0; p < 16; ++p)
      xtb[(size_t)(n0 + hi + p * 4) * 512 + c0 + lo] = f2s(t[lo][hi + p * 4]);
  } else {
    int i = (bid - 2048) * 256 + tid;              // i < 262144
    wqk[i] = f2s(i < 131072 ? wq[i] : wk[i - 131072]);
    if (i < 131072) { wvb[i] = f2s(wv[i]); wWb[i] = f2s(wW[i]); }
  }
}

// ---------------------------------------------------------------------------
// k_qkv: fused QK GEMM (+BN stats partials) and V GEMM.
//  y<4:  z_t[b][n][o] = sum_c x_t[b][n][c]*wqk[o][c], o0=y*128; epilogue also
//        atomicAdds per-channel sum/sumsq partials from the FP32 accumulators.
//  y>=4: v[b][cv][n] = sum_c wv[cv][c]*x_t[b][n][c] + bv[cv], cv0=(y-4)*128.
// ---------------------------------------------------------------------------
__global__ __launch_bounds__(256) void k_qkv(
    const unsigned short* __restrict__ xt, const unsigned short* __restrict__ wqk,
    const unsigned short* __restrict__ wvb, const float* __restrict__ bv,
    unsigned short* __restrict__ zt, unsigned short* __restrict__ v,
    float* __restrict__ stat)
{
  __shared__ __align__(16) unsigned short As[128 * 64], Bs[128 * 64];
  f32x4 acc[16] = {};
  const int b = blockIdx.z, n0 = blockIdx.x * 128, t = blockIdx.y;
  const int lane = threadIdx.x & 63, wave = threadIdx.x >> 6;
  const int lr = lane & 15, quad = lane >> 4;
  const int wm = (wave >> 1) * 64, wn = (wave & 1) * 64;

  if (t < 4) {
    const int o0 = t * 128;
    gemm_core_async<128, 128, 64>(xt + ((size_t)b * 4096 + n0) * 512, 512,
                                  wqk + (size_t)o0 * 512, 512, 512, As, Bs, acc);
    float s[4] = {}, ss[4] = {};
#pragma unroll
    for (int i = 0; i < 4; ++i)
#pragma unroll
      for (int j = 0; j < 4; ++j)
#pragma unroll
        for (int r = 0; r < 4; ++r) {
          float a = acc[i * 4 + j][r];
          int row = wm + i * 16 + quad * 4 + r, col = wn + j * 16 + lr;
          zt[((size_t)b * 4096 + n0 + row) * 512 + o0 + col] = f2s(a);
          s[j] += a; ss[j] += a * a;
        }
    // reduce over the 4 quads (rows of this wave), then atomic per channel
#pragma unroll
    for (int j = 0; j < 4; ++j) {
      s[j]  += __shfl_down(s[j], 32, 64);  s[j]  += __shfl_down(s[j], 16, 64);
      ss[j] += __shfl_down(ss[j], 32, 64); ss[j] += __shfl_down(ss[j], 16, 64);
      if (quad == 0) {
        int o = o0 + wn + j * 16 + lr;
        atomicAdd(&stat[o * 2], s[j]);
        atomicAdd(&stat[o * 2 + 1], ss[j]);
      }
    }
  } else {
    const int cv0 = (t - 4) * 128;
    gemm_core_async<128, 128, 64>(wvb + (size_t)cv0 * 512, 512,
                                  xt + ((size_t)b * 4096 + n0) * 512, 512, 512,
                                  As, Bs, acc);
#pragma unroll
    for (int i = 0; i < 4; ++i)
#pragma unroll
      for (int j = 0; j < 4; ++j)
#pragma unroll
        for (int r = 0; r < 4; ++r) {
          int row = wm + i * 16 + quad * 4 + r, col = wn + j * 16 + lr;
          v[((size_t)b * 256 + cv0 + row) * 4096 + n0 + col] =
              f2s(acc[i * 4 + j][r] + bv[cv0 + row]);
        }
  }
}

// ---------------------------------------------------------------------------
// BN+ReLU: q_t[n][c] / k_t[n][c] bf16 from z_t columns (stats now fp32-exact).
// ---------------------------------------------------------------------------
__global__ __launch_bounds__(256) void k_bnrelu(
    const unsigned short* __restrict__ zt, const float* __restrict__ stats_raw,
    const float* __restrict__ gq, const float* __restrict__ betaq,
    const float* __restrict__ gk, const float* __restrict__ betak,
    unsigned short* __restrict__ qt, unsigned short* __restrict__ kt)
{
  const int t = threadIdx.x;
  const float mA = stats_raw[t * 2] * (1.f / 16384.f);
  const float vA = stats_raw[t * 2 + 1] * (1.f / 16384.f) - mA * mA;
  const float scA = rsqrtf(vA + 1e-5f) * gq[t], beA = betaq[t];
  const float mB = stats_raw[(t + 256) * 2] * (1.f / 16384.f);
  const float vB = stats_raw[(t + 256) * 2 + 1] * (1.f / 16384.f) - mB * mB;
  const float scB = rsqrtf(vB + 1e-5f) * gk[t], beB = betak[t];
  const int r0 = blockIdx.x * 64;
  for (int r = r0; r < r0 + 64; ++r) {
    float a = s2f(zt[(size_t)r * 512 + t]);
    qt[(size_t)r * 256 + t] = f2s(fmaxf((a - mA) * scA + beA, 0.f));
    float c = s2f(zt[(size_t)r * 512 + t + 256]);
    kt[(size_t)r * 256 + t] = f2s(fmaxf((c - mB) * scB + beB, 0.f));
  }
}

// ---------------------------------------------------------------------------
// Scores+exp (all batches): P[b][n][m] = exp(s/16 - 20),
// s = sum_c kt[b,n][c] qt[b,m][c]. Fixed-shift softmax (q,k>=0 -> s in
// [0,~30]; shift-invariant, never over/underflows). exp via v_exp_f32 on
// exp2-domain fma; row sums from fp32 p (bf16-rounding noise averages out
// over 4096 terms).
// ---------------------------------------------------------------------------
__global__ __launch_bounds__(256) void k_sc(
    const unsigned short* __restrict__ qt, const unsigned short* __restrict__ kt,
    unsigned short* __restrict__ P, float* __restrict__ lsum)
{
  __shared__ __align__(16) unsigned short As[128 * 64], Bs[128 * 64];
  f32x4 acc[16] = {};
  const int b = blockIdx.z, m0 = blockIdx.x * 128, n0 = blockIdx.y * 128;
  gemm_core_async<128, 128, 64>(kt + ((size_t)b * 4096 + n0) * 256, 256,
                                qt + ((size_t)b * 4096 + m0) * 256, 256, 256,
                                As, Bs, acc);
  const int lane = threadIdx.x & 63, wave = threadIdx.x >> 6;
  const int lr = lane & 15, quad = lane >> 4;
  const int wm = (wave >> 1) * 64, wn = (wave & 1) * 64;
  unsigned short* Pb = P + (size_t)b * 16777216;
  float* l = lsum + b * 4096;
  const float C1 = 0.0625f * 1.44269504f;    // log2(e)/16
  const float C0 = -20.0f * 1.44269504f;     // -20*log2(e)
#pragma unroll
  for (int i = 0; i < 4; ++i)
#pragma unroll
    for (int r = 0; r < 4; ++r) {
      int row = wm + i * 16 + quad * 4 + r;
      float rs = 0.f;
#pragma unroll
      for (int j = 0; j < 4; ++j) {
        float p = __builtin_amdgcn_exp2f(fmaf(acc[i * 4 + j][r], C1, C0));
        Pb[(size_t)(n0 + row) * 4096 + m0 + wn + j * 16 + lr] = f2s(p);
        rs += p;
      }
      rs += __shfl_down(rs, 8, 16);
      rs += __shfl_down(rs, 4, 16);
      rs += __shfl_down(rs, 2, 16);
      rs += __shfl_down(rs, 1, 16);
      if (lr == 0) atomicAdd(&l[n0 + row], rs);
    }
}

// ---------------------------------------------------------------------------
// Context partials (all batches, K-split 4): m-range [split*1024, +1024):
//   opart[split][b][n][c] = sum_m P[b][n][m] v[b][c][m]  (fp32)
// grid (4 splits, 32 n-tiles, b*2+ctile), tile 128n x 128c -> 1024 blocks.
// ---------------------------------------------------------------------------
__global__ __launch_bounds__(256) void k_cx(
    const unsigned short* __restrict__ P, const unsigned short* __restrict__ v,
    float* __restrict__ opart)
{
  __shared__ __align__(16) unsigned short As[128 * 64], Bs[128 * 64];
  f32x4 acc[16] = {};
  const int split = blockIdx.x, n0 = blockIdx.y * 128;
  const int b = blockIdx.z >> 1, c0 = (blockIdx.z & 1) * 128;
  const int m0 = split * 1024;
  gemm_core_async<128, 128, 64>(
      P + ((size_t)b * 4096 + n0) * 4096 + m0, 4096,
      v + ((size_t)b * 256 + c0) * 4096 + m0, 4096, 1024, As, Bs, acc);
  const int lane = threadIdx.x & 63, wave = threadIdx.x >> 6;
  const int lr = lane & 15, quad = lane >> 4;
  const int wm = (wave >> 1) * 64, wn = (wave & 1) * 64;
  float* op = opart + (size_t)(split * 4 + b) * 1048576;
#pragma unroll
  for (int i = 0; i < 4; ++i)
#pragma unroll
    for (int j = 0; j < 4; ++j)
#pragma unroll
      for (int r = 0; r < 4; ++r) {
        int row = wm + i * 16 + quad * 4 + r, col = wn + j * 16 + lr;
        op[(size_t)(n0 + row) * 256 + c0 + col] = acc[i * 4 + j][r];
      }
}

// ---------------------------------------------------------------------------
// Reduce splits + softmax-normalize: ctx[b,n][c] = (sum_s opart[s][b][n][c])/l
// grid 16384 blocks (b*4096+n), 256 threads (c). Coalesced.
// ---------------------------------------------------------------------------
__global__ __launch_bounds__(256) void k_red(
    const float* __restrict__ opart, const float* __restrict__ lsum,
    unsigned short* __restrict__ ctx)
{
  const int g = blockIdx.x, c = threadIdx.x;     // g = b*4096 + n
  const int b = g >> 12;
  const size_t idx = (size_t)g * 256 + c;
  const size_t pidx = ((size_t)b * 1048576) + ((size_t)(g & 4095)) * 256 + c;
  float s = opart[pidx] + opart[pidx + 4194304] + opart[pidx + 8388608]
          + opart[pidx + 12582912];
  ctx[idx] = f2s(s / lsum[g]);
}

// ---------------------------------------------------------------------------
// Out: out[b][o][n] = sum_cv wW[o][cv] ctx[b,n][cv] + bW[o] + x[b][o][n]
// ---------------------------------------------------------------------------
__global__ __launch_bounds__(256) void k_out(
    const unsigned short* __restrict__ wWb, const float* __restrict__ bW,
    const unsigned short* __restrict__ ctx, const float* __restrict__ x,
    float* __restrict__ out)
{
  __shared__ __align__(16) unsigned short As[128 * 64], Bs[128 * 64];
  f32x4 acc[16] = {};
  const int b = blockIdx.z, n0 = blockIdx.x * 128, o0 = blockIdx.y * 128;
  gemm_core_async<128, 128, 64>(wWb + (size_t)o0 * 256, 256,
                                ctx + ((size_t)b * 4096 + n0) * 256, 256, 256,
                                As, Bs, acc);
  const int lane = threadIdx.x & 63, wave = threadIdx.x >> 6;
  const int lr = lane & 15, quad = lane >> 4;
  const int wm = (wave >> 1) * 64, wn = (wave & 1) * 64;
#pragma unroll
  for (int i = 0; i < 4; ++i)
#pragma unroll
    for (int j = 0; j < 4; ++j)
#pragma unroll
      for (int r = 0; r < 4; ++r) {
        int row = wm + i * 16 + quad * 4 + r, col = wn + j * 16 + lr;
        size_t idx = ((size_t)b * 512 + o0 + row) * 4096 + n0 + col;
        out[idx] = acc[i * 4 + j][r] + bW[o0 + row] + x[idx];
      }
}

// ---------------------------------------------------------------------------
extern "C" void kernel_launch(void* const* d_in, const int* in_sizes, int n_in,
                              void* d_out, int out_size, void* d_ws, size_t ws_size,
                              hipStream_t stream)
{
  const float* x     = (const float*)d_in[0];
  const float* wq    = (const float*)d_in[1];
  // d_in[2] = bq: cancelled exactly by BN mean-subtraction
  const float* gq    = (const float*)d_in[3];
  const float* betaq = (const float*)d_in[4];
  const float* wk    = (const float*)d_in[5];
  // d_in[6] = bk: cancelled
  const float* gk    = (const float*)d_in[7];
  const float* betak = (const float*)d_in[8];
  const float* wv    = (const float*)d_in[9];
  const float* bv    = (const float*)d_in[10];
  const float* wW    = (const float*)d_in[11];
  const float* bW    = (const float*)d_in[12];
  float* out = (float*)d_out;

  // workspace layout (ws_size = 256 MiB)
  char* ws = (char*)d_ws;
  unsigned short* qt   = (unsigned short*)(ws);              //  8 MiB [4*4096,256]
  unsigned short* kt   = (unsigned short*)(ws + 8388608);    //  8 MiB
  unsigned short* v    = (unsigned short*)(ws + 16777216);   //  8 MiB [4,256,4096]
  unsigned short* ctx  = (unsigned short*)(ws + 25165824);   //  8 MiB [4*4096,256]
  unsigned short* wqk  = (unsigned short*)(ws + 33554432);   // 512 KiB [512,512]
  unsigned short* wvb  = (unsigned short*)(ws + 34078720);   // 256 KiB [256,512]
  unsigned short* wWb  = (unsigned short*)(ws + 34340864);   // 256 KiB [512,256]
  float*          stat = (float*)         (ws + 34603008);   //   4 KiB
  float*          lsum = (float*)         (ws + 34607104);   //  64 KiB [4][4096]
  float*          opart= (float*)         (ws + 35651584);   //  64 MiB [4][4][4096][256]
  unsigned short* xt   = (unsigned short*)(ws + 35651584);   // 16 MiB, aliases opart
  unsigned short* zt   = (unsigned short*)(ws + 52428800);   // 16 MiB, aliases opart
                                                             // (xt dead after k_qkv,
                                                             //  zt dead after k_bnrelu,
                                                             //  both before k_cx)
  unsigned short* P    = (unsigned short*)(ws + 102760448);  // 128 MiB [4,4096,4096]

  (void)hipMemsetAsync(stat, 0, 69632, stream);  // stat (4K) + pad + lsum (64K)
  k_pre  <<<3072, 256, 0, stream>>>(x, xt, wq, wk, wv, wW, wqk, wvb, wWb);
  k_qkv  <<<dim3(32, 6, 4), 256, 0, stream>>>(xt, wqk, wvb, bv, zt, v, stat);
  k_bnrelu<<<256, 256, 0, stream>>>(zt, stat, gq, betaq, gk, betak, qt, kt);
  k_sc   <<<dim3(32, 32, 4), 256, 0, stream>>>(qt, kt, P, lsum);
  k_cx   <<<dim3(4, 32, 8), 256, 0, stream>>>(P, v, opart);
  k_red  <<<16384, 256, 0, stream>>>(opart, lsum, ctx);
  k_out  <<<dim3(32, 4, 4), 256, 0, stream>>>(wWb, bW, ctx, x, out);
}